// Round 11
// baseline (282.600 us; speedup 1.0000x reference)
//
#include <hip/hip_runtime.h>
#include <math.h>

// Problem constants (B=8, S=2048, D=512)
#define B_ 8
#define S_ 2048
#define D_ 512
#define KTOP 204                      // int(2048*0.1)
#define QK_SCALE 0.044194173824159216f // 1/sqrt(512)

typedef short bfrag8 __attribute__((ext_vector_type(8)));   // 8 bf16 (4 VGPRs)
typedef float facc16 __attribute__((ext_vector_type(16)));  // 32x32 MFMA accumulator

// ---------- helpers ----------
__device__ __forceinline__ unsigned short f2bf(float f) {
  unsigned u = __float_as_uint(f);
  u += 0x7FFFu + ((u >> 16) & 1);   // RNE
  return (unsigned short)(u >> 16);
}

// order-preserving map: descending float order == descending uint order
__device__ __forceinline__ unsigned fkey(float f) {
  unsigned b = __float_as_uint(f);
  return (b & 0x80000000u) ? ~b : (b | 0x80000000u);
}
__device__ __forceinline__ float keyfloat(unsigned k) {
  unsigned b = (k & 0x80000000u) ? (k & 0x7FFFFFFFu) : ~k;
  return __uint_as_float(b);
}

__device__ __forceinline__ void load16(const unsigned short* g, unsigned short* l) {
  __builtin_amdgcn_global_load_lds(
      (const __attribute__((address_space(1))) void*)g,
      (__attribute__((address_space(3))) void*)l, 16, 0, 0);
}

// ---------- fp32 -> bf16 convert, Q and K in one launch ----------
__global__ __launch_bounds__(256) void cvt_qk(const float* __restrict__ Q,
                                              const float* __restrict__ K,
                                              unsigned short* __restrict__ Qb,
                                              unsigned short* __restrict__ Kb) {
  const float* in = blockIdx.y ? K : Q;
  unsigned short* out = blockIdx.y ? Kb : Qb;
  int i = (blockIdx.x * 256 + threadIdx.x) * 4;
  float4 v = *(const float4*)(in + i);
  ushort4 o;
  o.x = f2bf(v.x); o.y = f2bf(v.y); o.z = f2bf(v.z); o.w = f2bf(v.w);
  *(ushort4*)(out + i) = o;
}

// ---------- V [b][k][d] fp32 -> VT [b][d][k] bf16 ----------
__global__ __launch_bounds__(256) void transpose_v(const float* __restrict__ V,
                                                   unsigned short* __restrict__ VT) {
  __shared__ float tile[32][33];
  int b = blockIdx.z;
  int d0 = blockIdx.x * 32, k0 = blockIdx.y * 32;
  const float* Vb = V + (size_t)b * S_ * D_;
  unsigned short* VTb = VT + (size_t)b * D_ * S_;
  int c = threadIdx.x & 31, r = threadIdx.x >> 5;
#pragma unroll
  for (int rr = 0; rr < 32; rr += 8)
    tile[r + rr][c] = Vb[(size_t)(k0 + r + rr) * D_ + d0 + c];
  __syncthreads();
#pragma unroll
  for (int rr = 0; rr < 32; rr += 8)
    VTb[(size_t)(d0 + r + rr) * S_ + k0 + c] = f2bf(tile[c][r + rr]);
}

// ---------- GEMM building blocks ----------
// R11 (kept verbatim): BK=64 dbuf + swizzle, MFMA 32x32x16. stage64 proven
// conflicts=0; fragment layouts per guide m74/m101 (HW-verified).

// stage one 128x64 k-tile of matrix M into LDS buffer dst (wave-uniform base).
__device__ __forceinline__ void stage64(const unsigned short* M, int ld, int k0,
                                        int tid, unsigned short* dst) {
  const int wave = tid >> 6;
  const int row = tid >> 3;                              // 0..31 per sweep
  const int col = ((tid & 7) ^ (row & 7)) * 8;           // swizzled source chunk
  unsigned short* wdst = dst + wave * 512;               // 1KB per wave per sweep
  const unsigned short* src = M + (size_t)row * ld + k0 + col;
#pragma unroll
  for (int s = 0; s < 4; ++s)
    load16(src + (size_t)(s * 32) * ld, wdst + s * 2048);
}

// 16 MFMAs (32x32x16) over one 128x64 x 128x64 LDS tile pair (4 k-chunks of 16).
__device__ __forceinline__ void mfma_step64(const unsigned short* sA, const unsigned short* sB,
                                            int mrow, int nrow, int lane,
                                            facc16 (&acc)[2][2]) {
  const int l31 = lane & 31, b5 = lane >> 5, l7 = lane & 7;
#pragma unroll
  for (int c = 0; c < 4; ++c) {
    const int slot = ((c * 2 + b5) ^ l7) * 8;            // swizzled read slot
    bfrag8 af[2], bq[2];
#pragma unroll
    for (int i = 0; i < 2; ++i)
      af[i] = *(const bfrag8*)(sA + (mrow + 32 * i + l31) * 64 + slot);
#pragma unroll
    for (int j2 = 0; j2 < 2; ++j2)
      bq[j2] = *(const bfrag8*)(sB + (nrow + 32 * j2 + l31) * 64 + slot);
#pragma unroll
    for (int i = 0; i < 2; ++i)
#pragma unroll
      for (int j2 = 0; j2 < 2; ++j2)
        acc[i][j2] = __builtin_amdgcn_mfma_f32_32x32x16_bf16(af[i], bq[j2], acc[i][j2], 0, 0, 0);
  }
}

// gemm1 variant: grid (16,16,8); XCD swizzle — bz = j&7 so each batch pins to one
// XCD (Qb[b]+Kb[b] = 4 MB = one XCD L2); within XCD, by fastest.
__global__ __launch_bounds__(256) void gemm_qk(
    const unsigned short* __restrict__ A, int lda, long long astr,
    const unsigned short* __restrict__ Bm, int ldb, long long bstr,
    float* __restrict__ C, int ldc, long long cstr,
    int kdim, float scale) {
  const unsigned j = blockIdx.x + 16u * blockIdx.y + 256u * blockIdx.z;
  const unsigned bz = j & 7u;           // batch == XCD residue
  const unsigned q = j >> 3;            // [0,256)
  const unsigned by = q & 15u;          // m-tile
  const unsigned bx = q >> 4;           // n-tile [0,16)

  __shared__ unsigned short smA[2][128 * 64];
  __shared__ unsigned short smB[2][128 * 64];
  const int tid = threadIdx.x;
  const int wave = tid >> 6, lane = tid & 63;
  const unsigned short* Ab = A + (long long)bz * astr + (size_t)(by * 128) * lda;
  const unsigned short* Bb = Bm + (long long)bz * bstr + (size_t)(bx * 128) * ldb;
  const int mrow = 64 * (wave >> 1);
  const int nrow = 64 * (wave & 1);

  facc16 acc[2][2];
#pragma unroll
  for (int i = 0; i < 2; ++i)
#pragma unroll
    for (int j2 = 0; j2 < 2; ++j2)
#pragma unroll
      for (int r = 0; r < 16; ++r) acc[i][j2][r] = 0.f;

  stage64(Ab, lda, 0, tid, smA[0]);
  stage64(Bb, ldb, 0, tid, smB[0]);
  __syncthreads();

  for (int k0 = 0; k0 < kdim; k0 += 128) {
    stage64(Ab, lda, k0 + 64, tid, smA[1]);
    stage64(Bb, ldb, k0 + 64, tid, smB[1]);
    mfma_step64(smA[0], smB[0], mrow, nrow, lane, acc);
    __syncthreads();
    if (k0 + 128 < kdim) {
      stage64(Ab, lda, k0 + 128, tid, smA[0]);
      stage64(Bb, ldb, k0 + 128, tid, smB[0]);
    }
    mfma_step64(smA[1], smB[1], mrow, nrow, lane, acc);
    __syncthreads();
  }

  float* Cb = C + (long long)bz * cstr;
  const int mg = by * 128 + mrow;
  const int ng = bx * 128 + nrow;
  const int l31 = lane & 31, b5 = lane >> 5;
#pragma unroll
  for (int i = 0; i < 2; ++i)
#pragma unroll
    for (int j2 = 0; j2 < 2; ++j2)
#pragma unroll
      for (int r = 0; r < 16; ++r) {
        const int row = mg + 32 * i + (r & 3) + 8 * (r >> 2) + 4 * b5;
        const int col = ng + 32 * j2 + l31;
        Cb[(size_t)row * ldc + col] = acc[i][j2][r] * scale;
      }
}

// gemm2 variant: grid (4,16,8); bz = j&7 (batch pins to XCD, VT[b] 2 MB in L2).
__global__ __launch_bounds__(256) void gemm_pv(
    const unsigned short* __restrict__ A, int lda, long long astr,
    const unsigned short* __restrict__ Bm, int ldb, long long bstr,
    float* __restrict__ C, int ldc, long long cstr,
    int kdim, float scale) {
  const unsigned j = blockIdx.x + 4u * blockIdx.y + 64u * blockIdx.z;
  const unsigned bz = j & 7u;           // batch == XCD residue
  const unsigned q = j >> 3;            // [0,64)
  const unsigned bx = q & 3u;           // n-tile (fastest)
  const unsigned by = q >> 2;           // m-tile [0,16)

  __shared__ unsigned short smA[2][128 * 64];
  __shared__ unsigned short smB[2][128 * 64];
  const int tid = threadIdx.x;
  const int wave = tid >> 6, lane = tid & 63;
  const unsigned short* Ab = A + (long long)bz * astr + (size_t)(by * 128) * lda;
  const unsigned short* Bb = Bm + (long long)bz * bstr + (size_t)(bx * 128) * ldb;
  const int mrow = 64 * (wave >> 1);
  const int nrow = 64 * (wave & 1);

  facc16 acc[2][2];
#pragma unroll
  for (int i = 0; i < 2; ++i)
#pragma unroll
    for (int j2 = 0; j2 < 2; ++j2)
#pragma unroll
      for (int r = 0; r < 16; ++r) acc[i][j2][r] = 0.f;

  stage64(Ab, lda, 0, tid, smA[0]);
  stage64(Bb, ldb, 0, tid, smB[0]);
  __syncthreads();

  for (int k0 = 0; k0 < kdim; k0 += 128) {
    stage64(Ab, lda, k0 + 64, tid, smA[1]);
    stage64(Bb, ldb, k0 + 64, tid, smB[1]);
    mfma_step64(smA[0], smB[0], mrow, nrow, lane, acc);
    __syncthreads();
    if (k0 + 128 < kdim) {
      stage64(Ab, lda, k0 + 128, tid, smA[0]);
      stage64(Bb, ldb, k0 + 128, tid, smB[0]);
    }
    mfma_step64(smA[1], smB[1], mrow, nrow, lane, acc);
    __syncthreads();
  }

  float* Cb = C + (long long)bz * cstr;
  const int mg = by * 128 + mrow;
  const int ng = bx * 128 + nrow;
  const int l31 = lane & 31, b5 = lane >> 5;
#pragma unroll
  for (int i = 0; i < 2; ++i)
#pragma unroll
    for (int j2 = 0; j2 < 2; ++j2)
#pragma unroll
      for (int r = 0; r < 16; ++r) {
        const int row = mg + 32 * i + (r & 3) + 8 * (r >> 2) + 4 * b5;
        const int col = ng + 32 * j2 + l31;
        Cb[(size_t)row * ldc + col] = acc[i][j2][r] * scale;
      }
}

// ---------- 256-bin radix-select step ----------
// bins[256]: counts. Finds digit d* s.t. count(digit > d*) < krem <= count(digit >= d*).
// Returns d*; *krem_out = krem - count(digit > d*). No crossing -> 0 / 0.
__device__ __forceinline__ unsigned sel256(const unsigned* bins, int lane,
                                           unsigned krem, unsigned* krem_out) {
  const uint4 b = *(const uint4*)(bins + lane * 4);
  const unsigned s = b.x + b.y + b.z + b.w;
  unsigned t = s;
#pragma unroll
  for (int off = 1; off < 64; off <<= 1) {
    unsigned u = (unsigned)__shfl_down((int)t, off);
    t += (lane + off < 64) ? u : 0u;
  }
  const unsigned texcl = t - s;           // suffix over lanes > lane
  const unsigned c3 = texcl + b.w;        // count(digit >= lane*4+3)
  const unsigned c2 = c3 + b.z;
  const unsigned c1 = c2 + b.y;
  const unsigned c0 = c1 + b.x;
  unsigned pack = 0;                      // nonzero in at most one lane
  if (c0 >= krem && c1 < krem)    pack = ((krem - c1) << 8) | (lane * 4 + 0);
  if (c1 >= krem && c2 < krem)    pack = ((krem - c2) << 8) | (lane * 4 + 1);
  if (c2 >= krem && c3 < krem)    pack = ((krem - c3) << 8) | (lane * 4 + 2);
  if (c3 >= krem && texcl < krem) pack = ((krem - texcl) << 8) | (lane * 4 + 3);
#pragma unroll
  for (int off = 1; off < 64; off <<= 1)
    pack |= (unsigned)__shfl_xor((int)pack, off);
  *krem_out = pack >> 8;
  return pack & 255u;
}

// ---------- per-row exact top-204 + softmax-of-sparse; TWO waves per row ----------
// R12: split each row across 2 waves (16 elems/lane) to halve the per-wave
// critical path (R6's 1-wave form: ~575 VALU + ~60 dependent shuffles + 8KB
// load per wave, nothing saturated at 70us -> latency-bound serial chain).
// One shared 256-bin histogram per row; only wave h=0 runs sel256 and
// broadcasts (krem,digit) via LDS. Fixed wave-uniform barrier schedule:
// 5 histogram slots (slot0 = quantile digit; common rows: slots 1-2 finish the
// key, 3-4 barrier-only dummies; degenerate rows (never for this data) use
// slots 1-4 as the full exact 4-pass radix) -> no deadlock regardless of which
// row in the block is degenerate. Tie-break: min-extract runs intra-wave in
// whichever half owns the cut (no barriers in the variable-length loop).
// Selection math identical to R6 -> bit-identical output.
__global__ __launch_bounds__(256) void topk_softmax(float* __restrict__ scores) {
  __shared__ unsigned binsAll[2][256];    // one 256-bin histogram per row
  __shared__ unsigned xchg[2][4];         // per-row exchange: [0,1]=kmax/zsum, [2]=pack/cut, [3]=tc
  const int tid = threadIdx.x;
  const int wave = tid >> 6, lane = tid & 63;
  const int pair = wave >> 1, h = wave & 1;     // pair = row-in-block, h = half
  const long long row = (long long)blockIdx.x * 2 + pair;
  float* srow = scores + row * 2048 + h * 1024;
  unsigned* bins = binsAll[pair];
  unsigned* xch = xchg[pair];

  unsigned k[16];
#pragma unroll
  for (int c = 0; c < 2; ++c) {
    float4 a = *(const float4*)(srow + c * 512 + lane * 8);
    float4 b = *(const float4*)(srow + c * 512 + lane * 8 + 4);
    k[c * 8 + 0] = fkey(a.x); k[c * 8 + 1] = fkey(a.y);
    k[c * 8 + 2] = fkey(a.z); k[c * 8 + 3] = fkey(a.w);
    k[c * 8 + 4] = fkey(b.x); k[c * 8 + 5] = fkey(b.y);
    k[c * 8 + 6] = fkey(b.z); k[c * 8 + 7] = fkey(b.w);
  }

  // zero bins (128 threads/row x uint2) + per-wave kmax -> LDS
  {
    uint2 z; z.x = 0; z.y = 0;
    *(uint2*)(bins + (h * 64 + lane) * 2) = z;
  }
  unsigned kmax = 0;
#pragma unroll
  for (int i = 0; i < 16; ++i) kmax = max(kmax, k[i]);
#pragma unroll
  for (int off = 1; off < 64; off <<= 1)
    kmax = max(kmax, (unsigned)__shfl_xor((int)kmax, off));
  if (lane == 0) xch[h] = kmax;
  __syncthreads();                                       // B1
  kmax = max(xch[0], xch[1]);
  const float m = fmaxf(keyfloat(kmax), 0.f);

  // ---- slot 0: quantile digit t = (key>>16)-0xBF00, count only t in [1,255] ----
#pragma unroll
  for (int i = 0; i < 16; ++i) {
    const int t = (int)(k[i] >> 16) - 0xBF00;
    if (t >= 1) atomicAdd(&bins[min(t, 255)], 1u);
  }
  __syncthreads();                                       // B2
  if (h == 0) {
    unsigned kr;
    const unsigned d = sel256(bins, lane, KTOP, &kr);
    if (lane == 0) xch[2] = (kr << 8) | d;
    asm volatile("s_waitcnt lgkmcnt(0)" ::: "memory");   // order read-before-zero
    uint4 z4; z4.x = 0; z4.y = 0; z4.z = 0; z4.w = 0;
    *(uint4*)(bins + lane * 4) = z4;
  }
  __syncthreads();                                       // B3
  unsigned pack = xch[2];
  const unsigned d1 = pack & 255u;
  unsigned krem = pack >> 8;

  const bool fb = (d1 < 1u || d1 > 254u);                // never for this data
  unsigned prefix, mmask;
  if (!fb) { prefix = (0xBF00u + d1) << 16; mmask = 0xFFFF0000u; }
  else     { prefix = 0u; mmask = 0u; krem = KTOP; }

  // ---- slots 1..4: common = {bits15:8, bits7:0, dummy, dummy}; fb = 4x8-bit radix ----
  for (int s = 1; s <= 4; ++s) {
    const bool active = fb || (s <= 2);
    const int shift = fb ? (32 - 8 * s) : ((s == 1) ? 8 : 0);
    if (active) {
#pragma unroll
      for (int i = 0; i < 16; ++i)
        if ((k[i] & mmask) == prefix) atomicAdd(&bins[(k[i] >> shift) & 255u], 1u);
    }
    __syncthreads();                                     // B4/6/8/10
    if (h == 0 && active) {
      unsigned kr;
      const unsigned d = sel256(bins, lane, krem, &kr);
      if (lane == 0) xch[2] = (kr << 8) | d;
      asm volatile("s_waitcnt lgkmcnt(0)" ::: "memory");
      uint4 z4; z4.x = 0; z4.y = 0; z4.z = 0; z4.w = 0;
      *(uint4*)(bins + lane * 4) = z4;
    }
    __syncthreads();                                     // B5/7/9/11
    if (active) {
      pack = xch[2];
      prefix |= (pack & 255u) << shift;
      krem = pack >> 8;
      mmask |= 0xFFu << shift;
    }
  }
  const unsigned tkey = prefix;

  // ---- tie-break across the two halves: krem lowest-index ties ----
  unsigned tiem = 0;
#pragma unroll
  for (int i = 0; i < 16; ++i)
    if (k[i] == tkey) tiem |= 1u << i;
  unsigned tc = (unsigned)__popc(tiem);
#pragma unroll
  for (int off = 1; off < 64; off <<= 1)
    tc += (unsigned)__shfl_xor((int)tc, off);
  if (h == 0 && lane == 0) xch[3] = tc;
  __syncthreads();                                       // B12
  const unsigned tcA = xch[3];
  const int whichHalf = (krem <= tcA) ? 0 : 1;           // half containing the cut
  if (h == whichHalf) {
    unsigned need = whichHalf ? (krem - tcA) : krem;     // >=1 by construction
    unsigned cutl;
    for (;;) {
      unsigned myidx = 0xFFFFFFFFu;
      if (tiem) {
        int i = __ffs((int)tiem) - 1;
        myidx = (unsigned)(h * 1024) + ((unsigned)(i >> 3)) * 512u +
                (unsigned)lane * 8u + (unsigned)(i & 7);
      }
      unsigned minidx = myidx;
#pragma unroll
      for (int off = 1; off < 64; off <<= 1)
        minidx = min(minidx, (unsigned)__shfl_xor((int)minidx, off));
      if (--need == 0 || minidx == 0xFFFFFFFFu) { cutl = minidx; break; }
      if (myidx == minidx) tiem &= tiem - 1;             // consume in owning lane
    }
    if (lane == 0) xch[2] = cutl;
  }
  __syncthreads();                                       // B13
  const unsigned cut = xch[2];

  // ---- weights + cross-pair Z ----
  const float eqw = __expf(keyfloat(tkey) - m);
  const float base = __expf(-m);
  float zsum = 0.f;
#pragma unroll
  for (int i = 0; i < 16; ++i) {
    const unsigned key = k[i];
    const unsigned idx = (unsigned)(h * 1024) + ((unsigned)(i >> 3)) * 512u +
                         (unsigned)lane * 8u + (unsigned)(i & 7);
    float w;
    if (key > tkey) w = __expf(keyfloat(key) - m);
    else w = (key == tkey && idx <= cut) ? eqw : base;
    zsum += w;
    k[i] = __float_as_uint(w);              // stash unnormalized weight
  }
#pragma unroll
  for (int off = 1; off < 64; off <<= 1) zsum += __shfl_xor(zsum, off);
  if (lane == 0) xch[h] = __float_as_uint(zsum);
  __syncthreads();                                       // B14
  const float Z = __uint_as_float(xch[0]) + __uint_as_float(xch[1]);
  const float invZ = 1.f / Z;

  // attn row (bf16) reuses the front 4KB of this row's 8KB score slot
  unsigned short* arow = (unsigned short*)scores + row * 4096 + h * 1024;
#pragma unroll
  for (int c = 0; c < 2; ++c) {
    union { unsigned short u[8]; int4 v4; } pk;
#pragma unroll
    for (int j = 0; j < 8; ++j)
      pk.u[j] = f2bf(__uint_as_float(k[c * 8 + j]) * invZ);
    *(int4*)(arow + c * 512 + lane * 8) = pk.v4;
  }
}

// ---------- launch ----------
// ws layout (bytes): Qb[0,16MB) Kb[16,32MB) VT[32,48MB) scores/attn[48,176MB)
extern "C" void kernel_launch(void* const* d_in, const int* in_sizes, int n_in,
                              void* d_out, int out_size, void* d_ws, size_t ws_size,
                              hipStream_t stream) {
  const float* Q = (const float*)d_in[0];
  const float* K = (const float*)d_in[1];
  const float* V = (const float*)d_in[2];
  float* out = (float*)d_out;
  char* ws = (char*)d_ws;
  unsigned short* Qb = (unsigned short*)(ws);
  unsigned short* Kb = (unsigned short*)(ws + ((size_t)16 << 20));
  unsigned short* VT = (unsigned short*)(ws + ((size_t)32 << 20));
  float* scores = (float*)(ws + ((size_t)48 << 20));

  const int nel = B_ * S_ * D_;  // 8388608
  cvt_qk<<<dim3(nel / 1024, 2), 256, 0, stream>>>(Q, K, Qb, Kb);
  transpose_v<<<dim3(D_ / 32, S_ / 32, B_), 256, 0, stream>>>(V, VT);
  // scores[b][q][k] = sum_d Q[q][d]*K[k][d] * scale ; score row pitch = 2048 f32
  gemm_qk<<<dim3(S_ / 128, S_ / 128, B_), 256, 0, stream>>>(
      Qb, D_, (long long)S_ * D_, Kb, D_, (long long)S_ * D_,
      scores, S_, (long long)S_ * S_, D_, QK_SCALE);
  topk_softmax<<<B_ * S_ / 2, 256, 0, stream>>>(scores);
  // out[b][q][d] = sum_k attn[q][k]*VT[d][k] ; attn row pitch = 4096 bf16 (8KB slots)
  gemm_pv<<<dim3(D_ / 128, S_ / 128, B_), 256, 0, stream>>>(
      (const unsigned short*)scores, 4096, (long long)S_ * 4096,
      VT, S_, (long long)D_ * S_, out, D_, (long long)S_ * D_, S_, 1.0f);
}

// Round 12
// 275.041 us; speedup vs baseline: 1.0275x; 1.0275x over previous
//
#include <hip/hip_runtime.h>
#include <math.h>

// Problem constants (B=8, S=2048, D=512)
#define B_ 8
#define S_ 2048
#define D_ 512
#define KTOP 204                      // int(2048*0.1)
#define QK_SCALE 0.044194173824159216f // 1/sqrt(512)

typedef short bfrag8 __attribute__((ext_vector_type(8)));  // 8 bf16 (4 VGPRs)
typedef float facc4 __attribute__((ext_vector_type(4)));   // MFMA accumulator

// ---------- helpers ----------
__device__ __forceinline__ unsigned short f2bf(float f) {
  unsigned u = __float_as_uint(f);
  u += 0x7FFFu + ((u >> 16) & 1);   // RNE
  return (unsigned short)(u >> 16);
}

// order-preserving map: descending float order == descending uint order
__device__ __forceinline__ unsigned fkey(float f) {
  unsigned b = __float_as_uint(f);
  return (b & 0x80000000u) ? ~b : (b | 0x80000000u);
}
__device__ __forceinline__ float keyfloat(unsigned k) {
  unsigned b = (k & 0x80000000u) ? (k & 0x7FFFFFFFu) : ~k;
  return __uint_as_float(b);
}

__device__ __forceinline__ void load16(const unsigned short* g, unsigned short* l) {
  __builtin_amdgcn_global_load_lds(
      (const __attribute__((address_space(1))) void*)g,
      (__attribute__((address_space(3))) void*)l, 16, 0, 0);
}

// ---------- fused prep: {Q,K fp32->bf16} + {V -> VT bf16 transpose} ----------
// R13: one launch instead of two. Blocks [0,16384) do the elementwise convert
// (first 8192 = Q, next 8192 = K); blocks [16384,24576) do the 32x32 V-tile
// transpose. Both are BW-bound; fusing lets them overlap and removes one
// dispatch boundary from a 5-dispatch serial pipeline.
__global__ __launch_bounds__(256) void prep(const float* __restrict__ Q,
                                            const float* __restrict__ K,
                                            const float* __restrict__ V,
                                            unsigned short* __restrict__ Qb,
                                            unsigned short* __restrict__ Kb,
                                            unsigned short* __restrict__ VT) {
  __shared__ float tile[32][33];
  const unsigned b = blockIdx.x;
  if (b < 16384u) {
    const float* in = (b < 8192u) ? Q : K;
    unsigned short* out = (b < 8192u) ? Qb : Kb;
    const int i = (int)((b & 8191u) * 1024u + threadIdx.x * 4u);
    float4 v = *(const float4*)(in + i);
    ushort4 o;
    o.x = f2bf(v.x); o.y = f2bf(v.y); o.z = f2bf(v.z); o.w = f2bf(v.w);
    *(ushort4*)(out + i) = o;
  } else {
    const unsigned t = b - 16384u;
    const int d0 = (int)(t & 15u) * 32;          // 16 d-tiles
    const int k0 = (int)((t >> 4) & 63u) * 32;   // 64 k-tiles
    const int bz = (int)(t >> 10);               // 8 batches
    const float* Vb = V + (size_t)bz * S_ * D_;
    unsigned short* VTb = VT + (size_t)bz * D_ * S_;
    const int c = threadIdx.x & 31, r = threadIdx.x >> 5;
#pragma unroll
    for (int rr = 0; rr < 32; rr += 8)
      tile[r + rr][c] = Vb[(size_t)(k0 + r + rr) * D_ + d0 + c];
    __syncthreads();
#pragma unroll
    for (int rr = 0; rr < 32; rr += 8)
      VTb[(size_t)(d0 + r + rr) * S_ + k0 + c] = f2bf(tile[c][r + rr]);
  }
}

// ---------- GEMM building blocks (R9 verbatim — best measured: total 270.8) ----------
// BK=64 double-buffered, 16x16x32 MFMA, T2 XOR swizzle (both-sides): global
// SOURCE chunk pre-swizzled ((l&7)^(row&7)), LDS dest linear (global_load_lds
// requirement), ds_read slot applies the same involution ((c*4+quad)^(l15&7)).
// Measured: SQ_LDS_BANK_CONFLICT = 0, gemm_qk ~59.5us. Do not touch.

// stage one 128x64 k-tile of matrix M into LDS buffer dst (wave-uniform base).
__device__ __forceinline__ void stage64(const unsigned short* M, int ld, int k0,
                                        int tid, unsigned short* dst) {
  const int wave = tid >> 6;
  const int row = tid >> 3;                              // 0..31 per sweep
  const int col = ((tid & 7) ^ (row & 7)) * 8;           // swizzled source chunk
  unsigned short* wdst = dst + wave * 512;               // 1KB per wave per sweep
  const unsigned short* src = M + (size_t)row * ld + k0 + col;
#pragma unroll
  for (int s = 0; s < 4; ++s)
    load16(src + (size_t)(s * 32) * ld, wdst + s * 2048);
}

// 32 MFMAs over one 128x64 x 128x64 LDS tile pair (2 k-chunks of 32).
__device__ __forceinline__ void mfma_step64(const unsigned short* sA, const unsigned short* sB,
                                            int mrow, int nrow, int l15, int quad,
                                            facc4 (&acc)[4][4]) {
#pragma unroll
  for (int c = 0; c < 2; ++c) {
    const int slot = ((c * 4 + quad) ^ (l15 & 7)) * 8;   // swizzled read slot
    bfrag8 af[4], bq[4];
#pragma unroll
    for (int i = 0; i < 4; ++i)
      af[i] = *(const bfrag8*)(sA + (mrow + 16 * i + l15) * 64 + slot);
#pragma unroll
    for (int j2 = 0; j2 < 4; ++j2)
      bq[j2] = *(const bfrag8*)(sB + (nrow + 16 * j2 + l15) * 64 + slot);
#pragma unroll
    for (int i = 0; i < 4; ++i)
#pragma unroll
      for (int j2 = 0; j2 < 4; ++j2)
        acc[i][j2] = __builtin_amdgcn_mfma_f32_16x16x32_bf16(af[i], bq[j2], acc[i][j2], 0, 0, 0);
  }
}

// gemm1 variant: grid (16,16,8); XCD swizzle — bz = j&7 so each batch pins to one
// XCD (Qb[b]+Kb[b] = 4 MB = one XCD L2); within XCD, by fastest.
__global__ __launch_bounds__(256) void gemm_qk(
    const unsigned short* __restrict__ A, int lda, long long astr,
    const unsigned short* __restrict__ Bm, int ldb, long long bstr,
    float* __restrict__ C, int ldc, long long cstr,
    int kdim, float scale) {
  const unsigned j = blockIdx.x + 16u * blockIdx.y + 256u * blockIdx.z;
  const unsigned bz = j & 7u;           // batch == XCD residue
  const unsigned q = j >> 3;            // [0,256)
  const unsigned by = q & 15u;          // m-tile
  const unsigned bx = q >> 4;           // n-tile [0,16)

  __shared__ unsigned short smA[2][128 * 64];
  __shared__ unsigned short smB[2][128 * 64];
  const int tid = threadIdx.x;
  const int wave = tid >> 6, lane = tid & 63;
  const int quad = lane >> 4, l15 = lane & 15;
  const unsigned short* Ab = A + (long long)bz * astr + (size_t)(by * 128) * lda;
  const unsigned short* Bb = Bm + (long long)bz * bstr + (size_t)(bx * 128) * ldb;
  const int mrow = 64 * (wave >> 1);
  const int nrow = 64 * (wave & 1);

  facc4 acc[4][4];
  const facc4 fzero = {0.f, 0.f, 0.f, 0.f};
#pragma unroll
  for (int i = 0; i < 4; ++i)
#pragma unroll
    for (int j2 = 0; j2 < 4; ++j2) acc[i][j2] = fzero;

  // prologue: stage k-tile 0 into buffer 0 (exposed once)
  stage64(Ab, lda, 0, tid, smA[0]);
  stage64(Bb, ldb, 0, tid, smB[0]);
  __syncthreads();

  // kdim is a multiple of 128 -> 2 k-tiles of 64 per trip, static buffers
  for (int k0 = 0; k0 < kdim; k0 += 128) {
    stage64(Ab, lda, k0 + 64, tid, smA[1]);
    stage64(Bb, ldb, k0 + 64, tid, smB[1]);
    mfma_step64(smA[0], smB[0], mrow, nrow, l15, quad, acc);
    __syncthreads();
    if (k0 + 128 < kdim) {
      stage64(Ab, lda, k0 + 128, tid, smA[0]);
      stage64(Bb, ldb, k0 + 128, tid, smB[0]);
    }
    mfma_step64(smA[1], smB[1], mrow, nrow, l15, quad, acc);
    __syncthreads();
  }

  float* Cb = C + (long long)bz * cstr;
  const int mg = by * 128 + mrow;
  const int ng = bx * 128 + nrow;
#pragma unroll
  for (int i = 0; i < 4; ++i)
#pragma unroll
    for (int j2 = 0; j2 < 4; ++j2)
#pragma unroll
      for (int r = 0; r < 4; ++r)
        Cb[(size_t)(mg + 16 * i + quad * 4 + r) * ldc + ng + 16 * j2 + l15] = acc[i][j2][r] * scale;
}

// gemm2 variant: grid (4,16,8); bz = j&7 (batch pins to XCD, VT[b] 2 MB in L2);
// within XCD, bx fastest so the 4 n-blocks sharing one 512 KB attn A-tile run
// back-to-back on the same XCD (A fetched from HBM once).
__global__ __launch_bounds__(256) void gemm_pv(
    const unsigned short* __restrict__ A, int lda, long long astr,
    const unsigned short* __restrict__ Bm, int ldb, long long bstr,
    float* __restrict__ C, int ldc, long long cstr,
    int kdim, float scale) {
  const unsigned j = blockIdx.x + 4u * blockIdx.y + 64u * blockIdx.z;
  const unsigned bz = j & 7u;           // batch == XCD residue
  const unsigned q = j >> 3;            // [0,64)
  const unsigned bx = q & 3u;           // n-tile (fastest)
  const unsigned by = q >> 2;           // m-tile [0,16)

  __shared__ unsigned short smA[2][128 * 64];
  __shared__ unsigned short smB[2][128 * 64];
  const int tid = threadIdx.x;
  const int wave = tid >> 6, lane = tid & 63;
  const int quad = lane >> 4, l15 = lane & 15;
  const unsigned short* Ab = A + (long long)bz * astr + (size_t)(by * 128) * lda;
  const unsigned short* Bb = Bm + (long long)bz * bstr + (size_t)(bx * 128) * ldb;
  const int mrow = 64 * (wave >> 1);
  const int nrow = 64 * (wave & 1);

  facc4 acc[4][4];
  const facc4 fzero = {0.f, 0.f, 0.f, 0.f};
#pragma unroll
  for (int i = 0; i < 4; ++i)
#pragma unroll
    for (int j2 = 0; j2 < 4; ++j2) acc[i][j2] = fzero;

  stage64(Ab, lda, 0, tid, smA[0]);
  stage64(Bb, ldb, 0, tid, smB[0]);
  __syncthreads();

  for (int k0 = 0; k0 < kdim; k0 += 128) {
    stage64(Ab, lda, k0 + 64, tid, smA[1]);
    stage64(Bb, ldb, k0 + 64, tid, smB[1]);
    mfma_step64(smA[0], smB[0], mrow, nrow, l15, quad, acc);
    __syncthreads();
    if (k0 + 128 < kdim) {
      stage64(Ab, lda, k0 + 128, tid, smA[0]);
      stage64(Bb, ldb, k0 + 128, tid, smB[0]);
    }
    mfma_step64(smA[1], smB[1], mrow, nrow, l15, quad, acc);
    __syncthreads();
  }

  float* Cb = C + (long long)bz * cstr;
  const int mg = by * 128 + mrow;
  const int ng = bx * 128 + nrow;
#pragma unroll
  for (int i = 0; i < 4; ++i)
#pragma unroll
    for (int j2 = 0; j2 < 4; ++j2)
#pragma unroll
      for (int r = 0; r < 4; ++r)
        Cb[(size_t)(mg + 16 * i + quad * 4 + r) * ldc + ng + 16 * j2 + l15] = acc[i][j2][r] * scale;
}

// ---------- 256-bin radix-select step ----------
// bins[256]: counts. Finds digit d* s.t. count(digit > d*) < krem <= count(digit >= d*).
// Returns d*; *krem_out = krem - count(digit > d*). No crossing -> 0 / 0.
__device__ __forceinline__ unsigned sel256(const unsigned* bins, int lane,
                                           unsigned krem, unsigned* krem_out) {
  const uint4 b = *(const uint4*)(bins + lane * 4);
  const unsigned s = b.x + b.y + b.z + b.w;
  unsigned t = s;
#pragma unroll
  for (int off = 1; off < 64; off <<= 1) {
    unsigned u = (unsigned)__shfl_down((int)t, off);
    t += (lane + off < 64) ? u : 0u;
  }
  const unsigned texcl = t - s;           // suffix over lanes > lane
  const unsigned c3 = texcl + b.w;        // count(digit >= lane*4+3)
  const unsigned c2 = c3 + b.z;
  const unsigned c1 = c2 + b.y;
  const unsigned c0 = c1 + b.x;
  unsigned pack = 0;                      // nonzero in at most one lane
  if (c0 >= krem && c1 < krem)    pack = ((krem - c1) << 8) | (lane * 4 + 0);
  if (c1 >= krem && c2 < krem)    pack = ((krem - c2) << 8) | (lane * 4 + 1);
  if (c2 >= krem && c3 < krem)    pack = ((krem - c3) << 8) | (lane * 4 + 2);
  if (c3 >= krem && texcl < krem) pack = ((krem - texcl) << 8) | (lane * 4 + 3);
#pragma unroll
  for (int off = 1; off < 64; off <<= 1)
    pack |= (unsigned)__shfl_xor((int)pack, off);
  *krem_out = pack >> 8;
  return pack & 255u;
}

// ---------- per-row exact top-204 + softmax-of-sparse; TWO waves per row ----------
// R12 (kept verbatim): 2 waves/row (16 elems/lane) halves the per-wave serial
// chain. Shared 256-bin histogram/row; h=0 wave runs sel256, broadcasts via
// LDS. Fixed wave-uniform barrier schedule (5 histogram slots; degenerate rows
// use slots 1-4 as full 4-pass radix — never taken for this data, no deadlock).
// Tie-break min-extract runs intra-wave in the half owning the cut.
__global__ __launch_bounds__(256) void topk_softmax(float* __restrict__ scores) {
  __shared__ unsigned binsAll[2][256];    // one 256-bin histogram per row
  __shared__ unsigned xchg[2][4];         // [0,1]=kmax/zsum, [2]=pack/cut, [3]=tc
  const int tid = threadIdx.x;
  const int wave = tid >> 6, lane = tid & 63;
  const int pair = wave >> 1, h = wave & 1;     // pair = row-in-block, h = half
  const long long row = (long long)blockIdx.x * 2 + pair;
  float* srow = scores + row * 2048 + h * 1024;
  unsigned* bins = binsAll[pair];
  unsigned* xch = xchg[pair];

  unsigned k[16];
#pragma unroll
  for (int c = 0; c < 2; ++c) {
    float4 a = *(const float4*)(srow + c * 512 + lane * 8);
    float4 b = *(const float4*)(srow + c * 512 + lane * 8 + 4);
    k[c * 8 + 0] = fkey(a.x); k[c * 8 + 1] = fkey(a.y);
    k[c * 8 + 2] = fkey(a.z); k[c * 8 + 3] = fkey(a.w);
    k[c * 8 + 4] = fkey(b.x); k[c * 8 + 5] = fkey(b.y);
    k[c * 8 + 6] = fkey(b.z); k[c * 8 + 7] = fkey(b.w);
  }

  // zero bins (128 threads/row x uint2) + per-wave kmax -> LDS
  {
    uint2 z; z.x = 0; z.y = 0;
    *(uint2*)(bins + (h * 64 + lane) * 2) = z;
  }
  unsigned kmax = 0;
#pragma unroll
  for (int i = 0; i < 16; ++i) kmax = max(kmax, k[i]);
#pragma unroll
  for (int off = 1; off < 64; off <<= 1)
    kmax = max(kmax, (unsigned)__shfl_xor((int)kmax, off));
  if (lane == 0) xch[h] = kmax;
  __syncthreads();                                       // B1
  kmax = max(xch[0], xch[1]);
  const float m = fmaxf(keyfloat(kmax), 0.f);

  // ---- slot 0: quantile digit t = (key>>16)-0xBF00, count only t in [1,255] ----
#pragma unroll
  for (int i = 0; i < 16; ++i) {
    const int t = (int)(k[i] >> 16) - 0xBF00;
    if (t >= 1) atomicAdd(&bins[min(t, 255)], 1u);
  }
  __syncthreads();                                       // B2
  if (h == 0) {
    unsigned kr;
    const unsigned d = sel256(bins, lane, KTOP, &kr);
    if (lane == 0) xch[2] = (kr << 8) | d;
    asm volatile("s_waitcnt lgkmcnt(0)" ::: "memory");   // order read-before-zero
    uint4 z4; z4.x = 0; z4.y = 0; z4.z = 0; z4.w = 0;
    *(uint4*)(bins + lane * 4) = z4;
  }
  __syncthreads();                                       // B3
  unsigned pack = xch[2];
  const unsigned d1 = pack & 255u;
  unsigned krem = pack >> 8;

  const bool fb = (d1 < 1u || d1 > 254u);                // never for this data
  unsigned prefix, mmask;
  if (!fb) { prefix = (0xBF00u + d1) << 16; mmask = 0xFFFF0000u; }
  else     { prefix = 0u; mmask = 0u; krem = KTOP; }

  // ---- slots 1..4: common = {bits15:8, bits7:0, dummy, dummy}; fb = 4x8-bit radix ----
  for (int s = 1; s <= 4; ++s) {
    const bool active = fb || (s <= 2);
    const int shift = fb ? (32 - 8 * s) : ((s == 1) ? 8 : 0);
    if (active) {
#pragma unroll
      for (int i = 0; i < 16; ++i)
        if ((k[i] & mmask) == prefix) atomicAdd(&bins[(k[i] >> shift) & 255u], 1u);
    }
    __syncthreads();                                     // B4/6/8/10
    if (h == 0 && active) {
      unsigned kr;
      const unsigned d = sel256(bins, lane, krem, &kr);
      if (lane == 0) xch[2] = (kr << 8) | d;
      asm volatile("s_waitcnt lgkmcnt(0)" ::: "memory");
      uint4 z4; z4.x = 0; z4.y = 0; z4.z = 0; z4.w = 0;
      *(uint4*)(bins + lane * 4) = z4;
    }
    __syncthreads();                                     // B5/7/9/11
    if (active) {
      pack = xch[2];
      prefix |= (pack & 255u) << shift;
      krem = pack >> 8;
      mmask |= 0xFFu << shift;
    }
  }
  const unsigned tkey = prefix;

  // ---- tie-break across the two halves: krem lowest-index ties ----
  unsigned tiem = 0;
#pragma unroll
  for (int i = 0; i < 16; ++i)
    if (k[i] == tkey) tiem |= 1u << i;
  unsigned tc = (unsigned)__popc(tiem);
#pragma unroll
  for (int off = 1; off < 64; off <<= 1)
    tc += (unsigned)__shfl_xor((int)tc, off);
  if (h == 0 && lane == 0) xch[3] = tc;
  __syncthreads();                                       // B12
  const unsigned tcA = xch[3];
  const int whichHalf = (krem <= tcA) ? 0 : 1;           // half containing the cut
  if (h == whichHalf) {
    unsigned need = whichHalf ? (krem - tcA) : krem;     // >=1 by construction
    unsigned cutl;
    for (;;) {
      unsigned myidx = 0xFFFFFFFFu;
      if (tiem) {
        int i = __ffs((int)tiem) - 1;
        myidx = (unsigned)(h * 1024) + ((unsigned)(i >> 3)) * 512u +
                (unsigned)lane * 8u + (unsigned)(i & 7);
      }
      unsigned minidx = myidx;
#pragma unroll
      for (int off = 1; off < 64; off <<= 1)
        minidx = min(minidx, (unsigned)__shfl_xor((int)minidx, off));
      if (--need == 0 || minidx == 0xFFFFFFFFu) { cutl = minidx; break; }
      if (myidx == minidx) tiem &= tiem - 1;             // consume in owning lane
    }
    if (lane == 0) xch[2] = cutl;
  }
  __syncthreads();                                       // B13
  const unsigned cut = xch[2];

  // ---- weights + cross-pair Z ----
  const float eqw = __expf(keyfloat(tkey) - m);
  const float base = __expf(-m);
  float zsum = 0.f;
#pragma unroll
  for (int i = 0; i < 16; ++i) {
    const unsigned key = k[i];
    const unsigned idx = (unsigned)(h * 1024) + ((unsigned)(i >> 3)) * 512u +
                         (unsigned)lane * 8u + (unsigned)(i & 7);
    float w;
    if (key > tkey) w = __expf(keyfloat(key) - m);
    else w = (key == tkey && idx <= cut) ? eqw : base;
    zsum += w;
    k[i] = __float_as_uint(w);              // stash unnormalized weight
  }
#pragma unroll
  for (int off = 1; off < 64; off <<= 1) zsum += __shfl_xor(zsum, off);
  if (lane == 0) xch[h] = __float_as_uint(zsum);
  __syncthreads();                                       // B14
  const float Z = __uint_as_float(xch[0]) + __uint_as_float(xch[1]);
  const float invZ = 1.f / Z;

  // attn row (bf16) reuses the front 4KB of this row's 8KB score slot
  unsigned short* arow = (unsigned short*)scores + row * 4096 + h * 1024;
#pragma unroll
  for (int c = 0; c < 2; ++c) {
    union { unsigned short u[8]; int4 v4; } pk;
#pragma unroll
    for (int j = 0; j < 8; ++j)
      pk.u[j] = f2bf(__uint_as_float(k[c * 8 + j]) * invZ);
    *(int4*)(arow + c * 512 + lane * 8) = pk.v4;
  }
}

// ---------- launch ----------
// ws layout (bytes): Qb[0,16MB) Kb[16,32MB) VT[32,48MB) scores/attn[48,176MB)
extern "C" void kernel_launch(void* const* d_in, const int* in_sizes, int n_in,
                              void* d_out, int out_size, void* d_ws, size_t ws_size,
                              hipStream_t stream) {
  const float* Q = (const float*)d_in[0];
  const float* K = (const float*)d_in[1];
  const float* V = (const float*)d_in[2];
  float* out = (float*)d_out;
  char* ws = (char*)d_ws;
  unsigned short* Qb = (unsigned short*)(ws);
  unsigned short* Kb = (unsigned short*)(ws + ((size_t)16 << 20));
  unsigned short* VT = (unsigned short*)(ws + ((size_t)32 << 20));
  float* scores = (float*)(ws + ((size_t)48 << 20));

  // fused convert + transpose: 16384 cvt blocks + 8192 transpose blocks
  prep<<<24576, 256, 0, stream>>>(Q, K, V, Qb, Kb, VT);
  // scores[b][q][k] = sum_d Q[q][d]*K[k][d] * scale ; score row pitch = 2048 f32
  gemm_qk<<<dim3(S_ / 128, S_ / 128, B_), 256, 0, stream>>>(
      Qb, D_, (long long)S_ * D_, Kb, D_, (long long)S_ * D_,
      scores, S_, (long long)S_ * S_, D_, QK_SCALE);
  topk_softmax<<<B_ * S_ / 2, 256, 0, stream>>>(scores);
  // out[b][q][d] = sum_k attn[q][k]*VT[d][k] ; attn row pitch = 4096 bf16 (8KB slots)
  gemm_pv<<<dim3(D_ / 128, S_ / 128, B_), 256, 0, stream>>>(
      (const unsigned short*)scores, 4096, (long long)S_ * 4096,
      VT, S_, (long long)D_ * S_, out, D_, (long long)S_ * D_, S_, 1.0f);
}